// Round 10
// baseline (1725.907 us; speedup 1.0000x reference)
//
#include <hip/hip_runtime.h>
#include <hip/hip_cooperative_groups.h>

namespace cg = cooperative_groups;

typedef unsigned short u16;
typedef unsigned int   u32;
typedef __attribute__((ext_vector_type(8))) short bf16x8;
typedef __attribute__((ext_vector_type(4))) float f32x4;

#define B_ROWS 32768
#define EPS_BN 1e-5f

// ---------- helpers ----------
__device__ __forceinline__ u16 f2bf(float f) {
  u32 u = __float_as_uint(f);
  u32 r = (u + 0x7FFFu + ((u >> 16) & 1u)) >> 16;   // RNE, no NaN inputs
  return (u16)r;
}
__device__ __forceinline__ u32 pk2bf(float a, float b) {
  return (u32)f2bf(a) | ((u32)f2bf(b) << 16);
}
__device__ __forceinline__ float bf2f(u16 h) {
  return __uint_as_float(((u32)h) << 16);
}

// GENUINE numpy-fp32 emulation — contraction disabled:
//   sp = RN(RN(px^2)+RN(py^2)); sm = RN(RN(mx^2)+RN(my^2))   [no fma]
//   dot = fma(py,my, RN(px*mx));  d2 = RN(RN(sp+sm) - 2*dot)
// NOTE: fma(dot,-2,spsm) == RN(spsm - RN(2*dot)) bit-exactly.
__device__ __forceinline__ float dcalc(float px, float py, float sp, float mx, float my) {
#pragma clang fp contract(off)
  float sm   = mx * mx + my * my;
  float pm   = px * mx;
  float dot  = __builtin_fmaf(py, my, pm);
  float spsm = sp + sm;
  return __builtin_fmaf(dot, -2.0f, spsm);
}
__device__ __forceinline__ float dcalc2(float px, float py, float sp, float mx, float my,
                                        float sm) {
#pragma clang fp contract(off)
  float pm   = px * mx;
  float dot  = __builtin_fmaf(py, my, pm);
  float spsm = sp + sm;
  return __builtin_fmaf(dot, -2.0f, spsm);
}
__device__ __forceinline__ float smcalc(float mx, float my) {
#pragma clang fp contract(off)
  return mx * mx + my * my;
}
__device__ __forceinline__ float spcalc(float px, float py) {
#pragma clang fp contract(off)
  return px * px + py * py;
}
#define MED3 __builtin_amdgcn_fmed3f

// ---------- KNN: 16 queries/block (4/wave), 64 STRIPED slices of 128 pts ----------
// (Verified @ R8/R9: ~98 us. Unchanged.)
__global__ __launch_bounds__(256, 8)
void knn_kernel(const float2* __restrict__ pos, const float2* __restrict__ mc,
                const float2* __restrict__ mv, float* __restrict__ knn_out,
                u16* __restrict__ X0)
{
  __shared__ float tv[16 * 65];       // 4.2 KB slice minima [q][s], pad->65
  __shared__ float tstS[16];
  __shared__ float qxS[16], qyS[16], qsS[16];
  __shared__ unsigned long long qmaskS[16];
  __shared__ int   qcnt[16];
  __shared__ int   ntaskS;

  const int t = threadIdx.x;
  const int g = t >> 6;               // wave = query group (4 queries)
  const int s = t & 63;               // striped slice id: points {2*(i*64+s), +1}
  const int q0 = blockIdx.x * 16;

  float px[4], py[4], sp[4];
#pragma unroll
  for (int j = 0; j < 4; ++j) {
    float2 p = pos[q0 + g * 4 + j];
    px[j] = p.x; py[j] = p.y; sp[j] = spcalc(p.x, p.y);
  }
#pragma unroll
  for (int j = 0; j < 4; ++j) {
    if (s == j) { qxS[g * 4 + j] = px[j]; qyS[g * 4 + j] = py[j]; qsS[g * 4 + j] = sp[j]; }
  }

  const float4* mc4 = (const float4*)mc;

  // ---- pass 1: slice min per query (z0 = exact slice min = prune certificate)
  float z0a[4], z0b[4];
#pragma unroll
  for (int j = 0; j < 4; ++j) { z0a[j] = __builtin_inff(); z0b[j] = __builtin_inff(); }

  float4 cur = mc4[s];                // pair index i*64+s, i=0
  for (int i = 0; i < 64; ++i) {
    float4 nxt = mc4[((i + 1) & 63) * 64 + s];
    float smA = smcalc(cur.x, cur.y);
    float smB = smcalc(cur.z, cur.w);
#pragma unroll
    for (int j = 0; j < 4; ++j) {
      float dA = dcalc2(px[j], py[j], sp[j], cur.x, cur.y, smA);
      z0a[j] = fminf(z0a[j], dA);
      float dB = dcalc2(px[j], py[j], sp[j], cur.z, cur.w, smB);
      z0b[j] = fminf(z0b[j], dB);
    }
    cur = nxt;
  }
  float z0[4];
#pragma unroll
  for (int j = 0; j < 4; ++j) {
    z0[j] = fminf(z0a[j], z0b[j]);
    tv[(g * 4 + j) * 65 + s] = z0[j];
  }
  __syncthreads();

  // ---- T' per query: exact 16th smallest of the 64 slice minima
  if (t < 16) {
    float ch[16];
#pragma unroll
    for (int j = 0; j < 16; ++j) ch[j] = __builtin_inff();
    for (int k = 0; k < 64; ++k) {
      float v = tv[t * 65 + k];
#pragma unroll
      for (int j = 15; j >= 1; --j) ch[j] = MED3(ch[j-1], v, ch[j]);
      ch[0] = fminf(ch[0], v);
    }
    tstS[t] = ch[15];
    qcnt[t] = 0;
    if (t == 0) ntaskS = 0;
  }
  __syncthreads();

  {
    float Tq[4];
#pragma unroll
    for (int j = 0; j < 4; ++j) Tq[j] = tstS[g * 4 + j];
    unsigned long long m;
#pragma unroll
    for (int j = 0; j < 4; ++j) {
      m = __ballot(z0[j] <= Tq[j]);
      if (s == j) qmaskS[g * 4 + j] = m;   // wave-uniform value, one lane stores
    }
  }
  __syncthreads();                    // qmaskS visible; tv reads done -> overlay ok

  u16* qcand = (u16*)tv;              // 16 x 64 u16 = 2 KB overlay
  u16* taskS = ((u16*)tv) + 1024;     // 1024 u16 task ids
  if (t < 16) {
    unsigned long long m = qmaskS[t];
    int c = __popcll(m);
    int off = atomicAdd(&ntaskS, c);
    u16 qb = (u16)(t << 6);
    while (m) {
      int b = (int)__builtin_ctzll(m);
      m &= m - 1;
      taskS[off++] = qb | (u16)b;
    }
  }
  __syncthreads();

  const int ntask = ntaskS;
  for (int i0 = t; i0 < ntask; i0 += 256) {
    const int task = taskS[i0];
    const int qrow = task >> 6;
    const int sl   = task & 63;
    const float qx = qxS[qrow], qy = qyS[qrow];
    const float qs = qsS[qrow], qT = tstS[qrow];
#pragma unroll 4
    for (int i = 0; i < 64; ++i) {
      float4 c2 = mc4[i * 64 + sl];
      const int pidx = 2 * (i * 64 + sl);
      float smA = smcalc(c2.x, c2.y);
      float smB = smcalc(c2.z, c2.w);
      float dA = dcalc2(qx, qy, qs, c2.x, c2.y, smA);
      float dB = dcalc2(qx, qy, qs, c2.z, c2.w, smB);
      if (dA <= qT) {
        int o = atomicAdd(&qcnt[qrow], 1);
        if (o < 64) qcand[qrow * 64 + o] = (u16)pidx;
      }
      if (dB <= qT) {
        int o = atomicAdd(&qcnt[qrow], 1);
        if (o < 64) qcand[qrow * 64 + o] = (u16)(pidx + 1);
      }
    }
  }
  __syncthreads();

  // ---- final: exact top-16 by (d asc, idx asc), 1 thread/query
  if (t < 16) {
    const int q = q0 + t;
    float2 p = pos[q];
    const float sq = spcalc(p.x, p.y);
    int cnt = qcnt[t]; if (cnt > 64) cnt = 64;
    float fd[16]; int fi[16];
#pragma unroll
    for (int j = 0; j < 16; ++j) { fd[j] = __builtin_inff(); fi[j] = 0x7fffffff; }
    for (int j = 0; j < cnt; ++j) {
      int ci = qcand[t * 64 + j];
      float2 m = mc[ci];
      float d = dcalc(p.x, p.y, sq, m.x, m.y);
      bool cc = (d < fd[15]) || (d == fd[15] && ci < fi[15]);
      if (cc) {
#pragma unroll
        for (int k = 15; k >= 1; --k) {
          bool cm = (d < fd[k-1]) || (d == fd[k-1] && ci < fi[k-1]);
          if (cc) {
            if (cm) { fd[k] = fd[k-1]; fi[k] = fi[k-1]; }
            else    { fd[k] = d;       fi[k] = ci;      }
          }
          cc = cm;
        }
        if (cc) { fd[0] = d; fi[0] = ci; }
      }
    }
    float* orow = knn_out + (size_t)q * 66;   // fp32 output 1 (knn_feat)
    u16*   xrow = X0 + (size_t)q * 96;        // bf16 MLP input, Kpad=96
    float2 pp; pp.x = p.x; pp.y = p.y;
    *(float2*)(&orow[0]) = pp;
    *(u32*)(&xrow[0]) = pk2bf(p.x, p.y);
#pragma unroll
    for (int j = 0; j < 16; ++j) {
      int ci = fi[j];
      float2 m = mc[ci], v = mv[ci];
      *(float2*)(&orow[2 + 4*j]) = m;
      *(float2*)(&orow[4 + 4*j]) = v;
      *(u32*)(&xrow[2 + 4*j]) = pk2bf(m.x, m.y);
      *(u32*)(&xrow[4 + 4*j]) = pk2bf(v.x, v.y);
    }
#pragma unroll
    for (int c = 33; c < 48; ++c) ((u32*)xrow)[c] = 0;  // u16 cols 66..95
  }
}

// ---------- weight prep: fp32 [K][N] -> bf16 transposed [N][Kpad] ----------
__global__ __launch_bounds__(256)
void prep_wt_all(const float* __restrict__ w1, const float* __restrict__ w2,
                 const float* __restrict__ w3, const float* __restrict__ w4,
                 const float* __restrict__ w5,
                 u16* __restrict__ wt1, u16* __restrict__ wt2, u16* __restrict__ wt3,
                 u16* __restrict__ wt4, u16* __restrict__ wt5)
{
  const int l = blockIdx.y;
  const float* w; u16* wt; int K, N, Kp;
  if (l == 0)      { w = w1; wt = wt1; K = 66;  N = 128; Kp = 96;  }
  else if (l == 1) { w = w2; wt = wt2; K = 128; N = 256; Kp = 128; }
  else if (l == 2) { w = w3; wt = wt3; K = 256; N = 512; Kp = 256; }
  else if (l == 3) { w = w4; wt = wt4; K = 512; N = 128; Kp = 512; }
  else             { w = w5; wt = wt5; K = 128; N = 64;  Kp = 128; }
  int i = blockIdx.x * 256 + threadIdx.x;
  if (i >= N * Kp) return;
  int n = i / Kp, kp = i - n * Kp;
  float v = (kp < K) ? w[(size_t)kp * N + n] : 0.0f;
  wt[i] = f2bf(v);
}

// ---------- shared GEMM building blocks (bit-identical R9 math) ----------
template<int KW, typename SCT>
__device__ __forceinline__ void fuse_prep(const float* __restrict__ psum,
                                          const float* __restrict__ psq,
                                          const float* __restrict__ gw,
                                          const float* __restrict__ bw,
                                          SCT& scA, SCT& ttA, const int t)
{
  const float invB = 1.0f / 32768.0f;
  for (int c = t; c < KW; c += 256) {
    float mean = psum[c] * invB;
    float var  = __fmaf_rn(-mean, mean, psq[c] * invB);  // biased
    float sc   = gw[c] * rsqrtf(var + EPS_BN);
    scA[c] = sc;
    ttA[c] = __fmaf_rn(-mean, sc, bw[c]);
  }
}

// One 128x64 output tile: 2-deep register pipeline, dbuf LDS, one barrier/K-step.
// Identical arithmetic to R9 (same FUSE op sequence, k-ascending MFMA chain,
// same epilogue + stats reduction).
template<int KW, bool FUSE, typename ASHT, typename BSHT, typename REDT, typename SCT>
__device__ __forceinline__ void gemm_tile(
    const u16* __restrict__ X, const u16* __restrict__ WT,
    const float* __restrict__ bias,
    u16* __restrict__ Z, int N,
    float* __restrict__ csum, float* __restrict__ csq,
    ASHT& Ash, BSHT& Bsh, REDT& redS, REDT& redQ, SCT& scA, SCT& ttA,
    const int m0, const int n0, const int t)
{
  constexpr int AST = 40;
  constexpr int NSTEP = KW / 32;
  const int wave = t >> 6;
  const int lane = t & 63;
  const int lr = lane & 15;
  const int qd = lane >> 4;

  f32x4 acc[2][4];
#pragma unroll
  for (int a = 0; a < 2; ++a)
#pragma unroll
    for (int b = 0; b < 4; ++b) {
      acc[a][b][0] = 0.f; acc[a][b][1] = 0.f; acc[a][b][2] = 0.f; acc[a][b][3] = 0.f;
    }

  const int sr = t >> 2;          // 0..63
  const int sk = (t & 3) * 8;     // 0,8,16,24

  const u16* Arow0 = &X[(size_t)(m0 + sr) * KW + sk];
  const u16* Arow1 = &X[(size_t)(m0 + sr + 64) * KW + sk];
  const u16* Brow  = &WT[(size_t)(n0 + sr) * KW + sk];

  auto fuseq = [&](uint4 gv, int kk) -> uint4 {
    u32 w[4] = {gv.x, gv.y, gv.z, gv.w};
    u32 o[4];
#pragma unroll
    for (int e = 0; e < 4; ++e) {
      float lo = bf2f((u16)(w[e] & 0xffffu));
      float hi = bf2f((u16)(w[e] >> 16));
      float yl = fmaxf(__fmaf_rn(lo, scA[kk + 2 * e],     ttA[kk + 2 * e]),     0.0f);
      float yh = fmaxf(__fmaf_rn(hi, scA[kk + 2 * e + 1], ttA[kk + 2 * e + 1]), 0.0f);
      o[e] = (u32)f2bf(yl) | ((u32)f2bf(yh) << 16);
    }
    uint4 r; r.x = o[0]; r.y = o[1]; r.z = o[2]; r.w = o[3];
    return r;
  };

  // prologue: tile 0 -> buf0; tile 1 -> registers
  {
    uint4 a0 = *(const uint4*)(Arow0);
    uint4 a1 = *(const uint4*)(Arow1);
    uint4 b0 = *(const uint4*)(Brow);
    if (FUSE) { a0 = fuseq(a0, sk); a1 = fuseq(a1, sk); }
    *(uint4*)(&Ash[0][sr * AST + sk]) = a0;
    *(uint4*)(&Ash[0][(sr + 64) * AST + sk]) = a1;
    *(uint4*)(&Bsh[0][sr * AST + sk]) = b0;
  }
  uint4 a0n = {}, a1n = {}, b0n = {};   // regs holding tile ts+1 during iter ts
  if (NSTEP > 1) {
    a0n = *(const uint4*)(Arow0 + 32);
    a1n = *(const uint4*)(Arow1 + 32);
    b0n = *(const uint4*)(Brow + 32);
  }
  __syncthreads();

  for (int ts = 0; ts < NSTEP; ++ts) {
    const int cur = ts & 1;

    uint4 La0 = a0n, La1 = a1n, Lb0 = b0n;
    if (ts + 2 < NSTEP) {
      const int ko = (ts + 2) * 32;
      La0 = *(const uint4*)(Arow0 + ko);
      La1 = *(const uint4*)(Arow1 + ko);
      Lb0 = *(const uint4*)(Brow + ko);
    }

    bf16x8 af0 = *(const bf16x8*)(&Ash[cur][(wave * 32 + lr) * AST + qd * 8]);
    bf16x8 af1 = *(const bf16x8*)(&Ash[cur][(wave * 32 + 16 + lr) * AST + qd * 8]);
#pragma unroll
    for (int ct = 0; ct < 4; ++ct) {
      bf16x8 bfr = *(const bf16x8*)(&Bsh[cur][(ct * 16 + lr) * AST + qd * 8]);
      acc[0][ct] = __builtin_amdgcn_mfma_f32_16x16x32_bf16(af0, bfr, acc[0][ct], 0, 0, 0);
      acc[1][ct] = __builtin_amdgcn_mfma_f32_16x16x32_bf16(af1, bfr, acc[1][ct], 0, 0, 0);
    }

    if (ts + 1 < NSTEP) {
      uint4 wa0 = a0n, wa1 = a1n, wb0 = b0n;   // tile ts+1, loaded one iter ago
      if (FUSE) {
        const int kk = (ts + 1) * 32 + sk;
        wa0 = fuseq(wa0, kk);
        wa1 = fuseq(wa1, kk);
      }
      *(uint4*)(&Ash[cur ^ 1][sr * AST + sk]) = wa0;
      *(uint4*)(&Ash[cur ^ 1][(sr + 64) * AST + sk]) = wa1;
      *(uint4*)(&Bsh[cur ^ 1][sr * AST + sk]) = wb0;
      __syncthreads();
      a0n = La0; a1n = La1; b0n = Lb0;
    }
  }

  // epilogue: bias, bf16 Z store, per-column partial sums
#pragma unroll
  for (int ct = 0; ct < 4; ++ct) {
    int cg = n0 + ct * 16 + lr;
    float bv = bias[cg];
    float s = 0.f, sqv = 0.f;
#pragma unroll
    for (int rt = 0; rt < 2; ++rt) {
#pragma unroll
      for (int r = 0; r < 4; ++r) {
        float z = acc[rt][ct][r] + bv;
        int row = m0 + wave * 32 + rt * 16 + qd * 4 + r;  // C/D: row=quad*4+reg, col=lane&15
        Z[(size_t)row * N + cg] = f2bf(z);
        s += z;
        sqv = __fmaf_rn(z, z, sqv);
      }
    }
    s   += __shfl_xor(s, 16);   s   += __shfl_xor(s, 32);
    sqv += __shfl_xor(sqv, 16); sqv += __shfl_xor(sqv, 32);
    if (qd == 0) { redS[wave][ct * 16 + lr] = s; redQ[wave][ct * 16 + lr] = sqv; }
  }
  __syncthreads();
  if (t < 64) {
    float s  = redS[0][t] + redS[1][t] + redS[2][t] + redS[3][t];
    float sv = redQ[0][t] + redQ[1][t] + redQ[2][t] + redQ[3][t];
    atomicAdd(&csum[n0 + t], s);
    atomicAdd(&csq[n0 + t], sv);
  }
}

// ---------- fallback standalone GEMM kernel (R9-equivalent) ----------
template<int KW, bool FUSE>
__global__ __launch_bounds__(256, 4)
void gemm_bn_kernel(const u16* __restrict__ X,
                    const u16* __restrict__ WT,
                    const float* __restrict__ bias,
                    const float* __restrict__ psum, const float* __restrict__ psq,
                    const float* __restrict__ gw,   const float* __restrict__ bw,
                    u16* __restrict__ Z, int N,
                    float* __restrict__ csum, float* __restrict__ csq)
{
  __shared__ u16 Ash[2][128 * 40];
  __shared__ u16 Bsh[2][64 * 40];
  __shared__ float redS[4][64];
  __shared__ float redQ[4][64];
  __shared__ float scA[FUSE ? KW : 1];
  __shared__ float ttA[FUSE ? KW : 1];
  const int t = threadIdx.x;
  if (FUSE) {
    fuse_prep<KW>(psum, psq, gw, bw, scA, ttA, t);
    __syncthreads();
  }
  gemm_tile<KW, FUSE>(X, WT, bias, Z, N, csum, csq, Ash, Bsh, redS, redQ, scA, ttA,
                      blockIdx.x * 128, blockIdx.y * 64, t);
}

// ---------- fallback final layer: fused BN5+ReLU + 64->2 GEMV ----------
__global__ __launch_bounds__(256)
void gemv6_kernel(const u16* __restrict__ Z5, const float* __restrict__ w6,
                  const float* __restrict__ b6,
                  const float* __restrict__ psum, const float* __restrict__ psq,
                  const float* __restrict__ gw,   const float* __restrict__ bw,
                  float* __restrict__ out)
{
  __shared__ float wsh[128];
  __shared__ float scs[64];
  __shared__ float tts[64];
  const int t = threadIdx.x;
  if (t < 128) wsh[t] = w6[t];
  if (t < 64) {
    const float invB = 1.0f / 32768.0f;
    float mean = psum[t] * invB;
    float var  = __fmaf_rn(-mean, mean, psq[t] * invB);
    float sc   = gw[t] * rsqrtf(var + EPS_BN);
    scs[t] = sc;
    tts[t] = __fmaf_rn(-mean, sc, bw[t]);
  }
  __syncthreads();
  const int q = blockIdx.x * 256 + t;
  const uint4* xv = (const uint4*)(Z5 + (size_t)q * 64);
  float a0 = 0.f, a1 = 0.f;
#pragma unroll
  for (int cc = 0; cc < 8; ++cc) {
    uint4 pk = xv[cc];
    u32 u[4] = {pk.x, pk.y, pk.z, pk.w};
#pragma unroll
    for (int uu = 0; uu < 4; ++uu) {
      int k = cc * 8 + uu * 2;
      float z0 = bf2f((u16)(u[uu] & 0xffffu));
      float z1 = bf2f((u16)(u[uu] >> 16));
      float x0 = fmaxf(__fmaf_rn(z0, scs[k],     tts[k]),     0.0f);
      float x1 = fmaxf(__fmaf_rn(z1, scs[k + 1], tts[k + 1]), 0.0f);
      x0 = bf2f(f2bf(x0));
      x1 = bf2f(f2bf(x1));
      a0 = __fmaf_rn(x0, wsh[2 * k + 0], a0);
      a1 = __fmaf_rn(x0, wsh[2 * k + 1], a1);
      a0 = __fmaf_rn(x1, wsh[2 * k + 2], a0);
      a1 = __fmaf_rn(x1, wsh[2 * k + 3], a1);
    }
  }
  float2 o; o.x = a0 + b6[0]; o.y = a1 + b6[1];
  ((float2*)out)[q] = o;
}

// ---------- cooperative megakernel: 5 GEMMs + gemv in ONE dispatch ----------
// R10: the GEMM chain modeled to ~30-50 us exec but measured ~200 -> the gap is
// 8 serialized dispatch boundaries (launch + full-GPU drain each). One
// cooperative kernel replaces 5 boundaries with grid.sync() (+ device fences
// for cross-XCD L2 visibility, G16). Per-tile math = gemm_tile (bit-identical).
__global__ __launch_bounds__(256, 4)
void mlp_mega(const u16* __restrict__ X0, u16* __restrict__ ZA, u16* __restrict__ ZB,
              const u16* __restrict__ WT1, const u16* __restrict__ WT2,
              const u16* __restrict__ WT3, const u16* __restrict__ WT4,
              const u16* __restrict__ WT5,
              const float* __restrict__ b1, const float* __restrict__ b2,
              const float* __restrict__ b3, const float* __restrict__ b4,
              const float* __restrict__ b5,
              const float* __restrict__ g1, const float* __restrict__ g2,
              const float* __restrict__ g3, const float* __restrict__ g4,
              const float* __restrict__ g5,
              const float* __restrict__ be1, const float* __restrict__ be2,
              const float* __restrict__ be3, const float* __restrict__ be4,
              const float* __restrict__ be5,
              const float* __restrict__ w6, const float* __restrict__ b6,
              float* __restrict__ stats, float* __restrict__ out)
{
  __shared__ u16 Ash[2][128 * 40];
  __shared__ u16 Bsh[2][64 * 40];
  __shared__ float redS[4][64];
  __shared__ float redQ[4][64];
  __shared__ float scA[512];
  __shared__ float ttA[512];

  cg::grid_group grid = cg::this_grid();
  const int t = threadIdx.x;
  const int nb = gridDim.x;

  float* s1 = stats;        float* s2 = stats + 128;  float* s3 = stats + 384;
  float* s4 = stats + 896;  float* s5 = stats + 1024;
  float* q1 = stats + 1088; float* q2 = stats + 1216; float* q3 = stats + 1472;
  float* q4 = stats + 1984; float* q5 = stats + 2112;

  // L1: X0 (K=96) -> ZA, N=128
  for (int tile = blockIdx.x; tile < 512; tile += nb) {
    gemm_tile<96, false>(X0, WT1, b1, ZA, 128, s1, q1, Ash, Bsh, redS, redQ,
                         scA, ttA, (tile & 255) * 128, (tile >> 8) * 64, t);
    __syncthreads();
  }
  __threadfence(); grid.sync(); __threadfence();

  // L2: ZA (K=128) -> ZB, N=256
  fuse_prep<128>(s1, q1, g1, be1, scA, ttA, t);
  __syncthreads();
  for (int tile = blockIdx.x; tile < 1024; tile += nb) {
    gemm_tile<128, true>(ZA, WT2, b2, ZB, 256, s2, q2, Ash, Bsh, redS, redQ,
                         scA, ttA, (tile & 255) * 128, (tile >> 8) * 64, t);
    __syncthreads();
  }
  __threadfence(); grid.sync(); __threadfence();

  // L3: ZB (K=256) -> ZA, N=512
  fuse_prep<256>(s2, q2, g2, be2, scA, ttA, t);
  __syncthreads();
  for (int tile = blockIdx.x; tile < 2048; tile += nb) {
    gemm_tile<256, true>(ZB, WT3, b3, ZA, 512, s3, q3, Ash, Bsh, redS, redQ,
                         scA, ttA, (tile & 255) * 128, (tile >> 8) * 64, t);
    __syncthreads();
  }
  __threadfence(); grid.sync(); __threadfence();

  // L4: ZA (K=512) -> ZB, N=128
  fuse_prep<512>(s3, q3, g3, be3, scA, ttA, t);
  __syncthreads();
  for (int tile = blockIdx.x; tile < 512; tile += nb) {
    gemm_tile<512, true>(ZA, WT4, b4, ZB, 128, s4, q4, Ash, Bsh, redS, redQ,
                         scA, ttA, (tile & 255) * 128, (tile >> 8) * 64, t);
    __syncthreads();
  }
  __threadfence(); grid.sync(); __threadfence();

  // L5: ZB (K=128) -> ZA, N=64
  fuse_prep<128>(s4, q4, g4, be4, scA, ttA, t);
  __syncthreads();
  for (int tile = blockIdx.x; tile < 256; tile += nb) {
    gemm_tile<128, true>(ZB, WT5, b5, ZA, 64, s5, q5, Ash, Bsh, redS, redQ,
                         scA, ttA, (tile & 255) * 128, (tile >> 8) * 64, t);
    __syncthreads();
  }
  __threadfence(); grid.sync(); __threadfence();

  // gemv6: BN5+ReLU + 64->2 (same math as gemv6_kernel); reuse scA LDS
  float* wsh = &scA[0];     // 128
  float* scs = &scA[128];   // 64
  float* tts = &scA[192];   // 64
  if (t < 128) wsh[t] = w6[t];
  if (t < 64) {
    const float invB = 1.0f / 32768.0f;
    float mean = s5[t] * invB;
    float var  = __fmaf_rn(-mean, mean, q5[t] * invB);
    float sc   = g5[t] * rsqrtf(var + EPS_BN);
    scs[t] = sc;
    tts[t] = __fmaf_rn(-mean, sc, be5[t]);
  }
  __syncthreads();
  for (int q = blockIdx.x * 256 + t; q < B_ROWS; q += nb * 256) {
    const uint4* xv = (const uint4*)(ZA + (size_t)q * 64);
    float a0 = 0.f, a1 = 0.f;
#pragma unroll
    for (int cc = 0; cc < 8; ++cc) {
      uint4 pk = xv[cc];
      u32 u[4] = {pk.x, pk.y, pk.z, pk.w};
#pragma unroll
      for (int uu = 0; uu < 4; ++uu) {
        int k = cc * 8 + uu * 2;
        float z0 = bf2f((u16)(u[uu] & 0xffffu));
        float z1 = bf2f((u16)(u[uu] >> 16));
        float x0 = fmaxf(__fmaf_rn(z0, scs[k],     tts[k]),     0.0f);
        float x1 = fmaxf(__fmaf_rn(z1, scs[k + 1], tts[k + 1]), 0.0f);
        x0 = bf2f(f2bf(x0));
        x1 = bf2f(f2bf(x1));
        a0 = __fmaf_rn(x0, wsh[2 * k + 0], a0);
        a1 = __fmaf_rn(x0, wsh[2 * k + 1], a1);
        a0 = __fmaf_rn(x1, wsh[2 * k + 2], a0);
        a1 = __fmaf_rn(x1, wsh[2 * k + 3], a1);
      }
    }
    float2 o; o.x = a0 + b6[0]; o.y = a1 + b6[1];
    ((float2*)out)[q] = o;
  }
}

// ---------- launch ----------
extern "C" void kernel_launch(void* const* d_in, const int* in_sizes, int n_in,
                              void* d_out, int out_size, void* d_ws, size_t ws_size,
                              hipStream_t stream)
{
  const float2* pos = (const float2*)d_in[0];
  const float2* mc  = (const float2*)d_in[1];
  const float2* mv  = (const float2*)d_in[2];
  const float* w1 = (const float*)d_in[3];  const float* b1 = (const float*)d_in[4];
  const float* w2 = (const float*)d_in[5];  const float* b2 = (const float*)d_in[6];
  const float* w3 = (const float*)d_in[7];  const float* b3 = (const float*)d_in[8];
  const float* w4 = (const float*)d_in[9];  const float* b4 = (const float*)d_in[10];
  const float* w5 = (const float*)d_in[11]; const float* b5 = (const float*)d_in[12];
  const float* w6 = (const float*)d_in[13]; const float* b6 = (const float*)d_in[14];
  const float* g1 = (const float*)d_in[15]; const float* be1 = (const float*)d_in[16];
  const float* g2 = (const float*)d_in[17]; const float* be2 = (const float*)d_in[18];
  const float* g3 = (const float*)d_in[19]; const float* be3 = (const float*)d_in[20];
  const float* g4 = (const float*)d_in[21]; const float* be4 = (const float*)d_in[22];
  const float* g5 = (const float*)d_in[23]; const float* be5 = (const float*)d_in[24];

  // ws layout (bf16): X0 6.29MB | ZA 33.55MB | ZB 33.55MB | WT1..5 | stats
  char* ws = (char*)d_ws;
  u16* X0   = (u16*)(ws + 0);
  u16* ZA   = (u16*)(ws + 6291456);
  u16* ZB   = (u16*)(ws + 39845888);
  u16* WT1  = (u16*)(ws + 73400320);
  u16* WT2  = (u16*)(ws + 73424896);
  u16* WT3  = (u16*)(ws + 73490432);
  u16* WT4  = (u16*)(ws + 73752576);
  u16* WT5  = (u16*)(ws + 73883648);
  float* stats = (float*)(ws + 73900032);
  float* s1 = stats;        float* s2 = stats + 128;  float* s3 = stats + 384;
  float* s4 = stats + 896;  float* s5 = stats + 1024;
  float* sqb = stats + 1088;
  float* q1 = sqb;          float* q2 = sqb + 128;    float* q3 = sqb + 384;
  float* q4 = sqb + 896;    float* q5 = sqb + 1024;

  float* outX = (float*)d_out;
  float* outK = outX + 2 * B_ROWS;

  hipMemsetAsync(stats, 0, 2176 * sizeof(float), stream);
  prep_wt_all<<<dim3(512, 5), 256, 0, stream>>>(w1, w2, w3, w4, w5, WT1, WT2, WT3, WT4, WT5);
  knn_kernel<<<dim3(2048), 256, 0, stream>>>(pos, mc, mv, outK, X0);

  // One cooperative dispatch for the whole MLP; fall back to the R9 chain on
  // any launch failure (capture-unsupported / occupancy rejection).
  void* kargs[] = {
    (void*)&X0, (void*)&ZA, (void*)&ZB,
    (void*)&WT1, (void*)&WT2, (void*)&WT3, (void*)&WT4, (void*)&WT5,
    (void*)&b1, (void*)&b2, (void*)&b3, (void*)&b4, (void*)&b5,
    (void*)&g1, (void*)&g2, (void*)&g3, (void*)&g4, (void*)&g5,
    (void*)&be1, (void*)&be2, (void*)&be3, (void*)&be4, (void*)&be5,
    (void*)&w6, (void*)&b6, (void*)&stats, (void*)&outX,
  };
  hipError_t ce = hipLaunchCooperativeKernel((void*)mlp_mega, dim3(1024), dim3(256),
                                             kargs, 0, stream);
  if (ce != hipSuccess) {
    (void)hipGetLastError();   // clear error state; run the R9-verified chain
    gemm_bn_kernel<96,  false><<<dim3(256, 2), 256, 0, stream>>>(
        X0, WT1, b1, nullptr, nullptr, nullptr, nullptr, ZA, 128, s1, q1);
    gemm_bn_kernel<128, true><<<dim3(256, 4), 256, 0, stream>>>(
        ZA, WT2, b2, s1, q1, g1, be1, ZB, 256, s2, q2);
    gemm_bn_kernel<256, true><<<dim3(256, 8), 256, 0, stream>>>(
        ZB, WT3, b3, s2, q2, g2, be2, ZA, 512, s3, q3);
    gemm_bn_kernel<512, true><<<dim3(256, 2), 256, 0, stream>>>(
        ZA, WT4, b4, s3, q3, g3, be3, ZB, 128, s4, q4);
    gemm_bn_kernel<128, true><<<dim3(256, 1), 256, 0, stream>>>(
        ZB, WT5, b5, s4, q4, g4, be4, ZA, 64, s5, q5);
    gemv6_kernel<<<dim3(128), 256, 0, stream>>>(ZA, w6, b6, s5, q5, g5, be5, outX);
  }

  (void)in_sizes; (void)n_in; (void)out_size; (void)ws_size;
}

// Round 11
// 299.658 us; speedup vs baseline: 5.7596x; 5.7596x over previous
//
#include <hip/hip_runtime.h>

typedef unsigned short u16;
typedef unsigned int   u32;
typedef __attribute__((ext_vector_type(8))) short bf16x8;
typedef __attribute__((ext_vector_type(4))) float f32x4;

#define B_ROWS 32768
#define EPS_BN 1e-5f

// ---------- helpers ----------
__device__ __forceinline__ u16 f2bf(float f) {
  u32 u = __float_as_uint(f);
  u32 r = (u + 0x7FFFu + ((u >> 16) & 1u)) >> 16;   // RNE, no NaN inputs
  return (u16)r;
}
__device__ __forceinline__ u32 pk2bf(float a, float b) {
  return (u32)f2bf(a) | ((u32)f2bf(b) << 16);
}
__device__ __forceinline__ float bf2f(u16 h) {
  return __uint_as_float(((u32)h) << 16);
}

// GENUINE numpy-fp32 emulation — contraction disabled:
//   sp = RN(RN(px^2)+RN(py^2)); sm = RN(RN(mx^2)+RN(my^2))   [no fma]
//   dot = fma(py,my, RN(px*mx));  d2 = RN(RN(sp+sm) - 2*dot)
// NOTE: fma(dot,-2,spsm) == RN(spsm - RN(2*dot)) bit-exactly.
__device__ __forceinline__ float dcalc(float px, float py, float sp, float mx, float my) {
#pragma clang fp contract(off)
  float sm   = mx * mx + my * my;
  float pm   = px * mx;
  float dot  = __builtin_fmaf(py, my, pm);
  float spsm = sp + sm;
  return __builtin_fmaf(dot, -2.0f, spsm);
}
__device__ __forceinline__ float dcalc2(float px, float py, float sp, float mx, float my,
                                        float sm) {
#pragma clang fp contract(off)
  float pm   = px * mx;
  float dot  = __builtin_fmaf(py, my, pm);
  float spsm = sp + sm;
  return __builtin_fmaf(dot, -2.0f, spsm);
}
__device__ __forceinline__ float smcalc(float mx, float my) {
#pragma clang fp contract(off)
  return mx * mx + my * my;
}
__device__ __forceinline__ float spcalc(float px, float py) {
#pragma clang fp contract(off)
  return px * px + py * py;
}
#define MED3 __builtin_amdgcn_fmed3f

// ---------- KNN: 16 queries/block (4/wave), 64 STRIPED slices of 128 pts ----------
// (Verified @ R8/R9: ~98 us. Unchanged.)
__global__ __launch_bounds__(256, 8)
void knn_kernel(const float2* __restrict__ pos, const float2* __restrict__ mc,
                const float2* __restrict__ mv, float* __restrict__ knn_out,
                u16* __restrict__ X0)
{
  __shared__ float tv[16 * 65];       // 4.2 KB slice minima [q][s], pad->65
  __shared__ float tstS[16];
  __shared__ float qxS[16], qyS[16], qsS[16];
  __shared__ unsigned long long qmaskS[16];
  __shared__ int   qcnt[16];
  __shared__ int   ntaskS;

  const int t = threadIdx.x;
  const int g = t >> 6;               // wave = query group (4 queries)
  const int s = t & 63;               // striped slice id: points {2*(i*64+s), +1}
  const int q0 = blockIdx.x * 16;

  float px[4], py[4], sp[4];
#pragma unroll
  for (int j = 0; j < 4; ++j) {
    float2 p = pos[q0 + g * 4 + j];
    px[j] = p.x; py[j] = p.y; sp[j] = spcalc(p.x, p.y);
  }
#pragma unroll
  for (int j = 0; j < 4; ++j) {
    if (s == j) { qxS[g * 4 + j] = px[j]; qyS[g * 4 + j] = py[j]; qsS[g * 4 + j] = sp[j]; }
  }

  const float4* mc4 = (const float4*)mc;

  // ---- pass 1: slice min per query (z0 = exact slice min = prune certificate)
  float z0a[4], z0b[4];
#pragma unroll
  for (int j = 0; j < 4; ++j) { z0a[j] = __builtin_inff(); z0b[j] = __builtin_inff(); }

  float4 cur = mc4[s];                // pair index i*64+s, i=0
  for (int i = 0; i < 64; ++i) {
    float4 nxt = mc4[((i + 1) & 63) * 64 + s];
    float smA = smcalc(cur.x, cur.y);
    float smB = smcalc(cur.z, cur.w);
#pragma unroll
    for (int j = 0; j < 4; ++j) {
      float dA = dcalc2(px[j], py[j], sp[j], cur.x, cur.y, smA);
      z0a[j] = fminf(z0a[j], dA);
      float dB = dcalc2(px[j], py[j], sp[j], cur.z, cur.w, smB);
      z0b[j] = fminf(z0b[j], dB);
    }
    cur = nxt;
  }
  float z0[4];
#pragma unroll
  for (int j = 0; j < 4; ++j) {
    z0[j] = fminf(z0a[j], z0b[j]);
    tv[(g * 4 + j) * 65 + s] = z0[j];
  }
  __syncthreads();

  // ---- T' per query: exact 16th smallest of the 64 slice minima
  if (t < 16) {
    float ch[16];
#pragma unroll
    for (int j = 0; j < 16; ++j) ch[j] = __builtin_inff();
    for (int k = 0; k < 64; ++k) {
      float v = tv[t * 65 + k];
#pragma unroll
      for (int j = 15; j >= 1; --j) ch[j] = MED3(ch[j-1], v, ch[j]);
      ch[0] = fminf(ch[0], v);
    }
    tstS[t] = ch[15];
    qcnt[t] = 0;
    if (t == 0) ntaskS = 0;
  }
  __syncthreads();

  {
    float Tq[4];
#pragma unroll
    for (int j = 0; j < 4; ++j) Tq[j] = tstS[g * 4 + j];
    unsigned long long m;
#pragma unroll
    for (int j = 0; j < 4; ++j) {
      m = __ballot(z0[j] <= Tq[j]);
      if (s == j) qmaskS[g * 4 + j] = m;   // wave-uniform value, one lane stores
    }
  }
  __syncthreads();                    // qmaskS visible; tv reads done -> overlay ok

  u16* qcand = (u16*)tv;              // 16 x 64 u16 = 2 KB overlay
  u16* taskS = ((u16*)tv) + 1024;     // 1024 u16 task ids
  if (t < 16) {
    unsigned long long m = qmaskS[t];
    int c = __popcll(m);
    int off = atomicAdd(&ntaskS, c);
    u16 qb = (u16)(t << 6);
    while (m) {
      int b = (int)__builtin_ctzll(m);
      m &= m - 1;
      taskS[off++] = qb | (u16)b;
    }
  }
  __syncthreads();

  const int ntask = ntaskS;
  for (int i0 = t; i0 < ntask; i0 += 256) {
    const int task = taskS[i0];
    const int qrow = task >> 6;
    const int sl   = task & 63;
    const float qx = qxS[qrow], qy = qyS[qrow];
    const float qs = qsS[qrow], qT = tstS[qrow];
#pragma unroll 4
    for (int i = 0; i < 64; ++i) {
      float4 c2 = mc4[i * 64 + sl];
      const int pidx = 2 * (i * 64 + sl);
      float smA = smcalc(c2.x, c2.y);
      float smB = smcalc(c2.z, c2.w);
      float dA = dcalc2(qx, qy, qs, c2.x, c2.y, smA);
      float dB = dcalc2(qx, qy, qs, c2.z, c2.w, smB);
      if (dA <= qT) {
        int o = atomicAdd(&qcnt[qrow], 1);
        if (o < 64) qcand[qrow * 64 + o] = (u16)pidx;
      }
      if (dB <= qT) {
        int o = atomicAdd(&qcnt[qrow], 1);
        if (o < 64) qcand[qrow * 64 + o] = (u16)(pidx + 1);
      }
    }
  }
  __syncthreads();

  // ---- final: exact top-16 by (d asc, idx asc), 1 thread/query
  if (t < 16) {
    const int q = q0 + t;
    float2 p = pos[q];
    const float sq = spcalc(p.x, p.y);
    int cnt = qcnt[t]; if (cnt > 64) cnt = 64;
    float fd[16]; int fi[16];
#pragma unroll
    for (int j = 0; j < 16; ++j) { fd[j] = __builtin_inff(); fi[j] = 0x7fffffff; }
    for (int j = 0; j < cnt; ++j) {
      int ci = qcand[t * 64 + j];
      float2 m = mc[ci];
      float d = dcalc(p.x, p.y, sq, m.x, m.y);
      bool cc = (d < fd[15]) || (d == fd[15] && ci < fi[15]);
      if (cc) {
#pragma unroll
        for (int k = 15; k >= 1; --k) {
          bool cm = (d < fd[k-1]) || (d == fd[k-1] && ci < fi[k-1]);
          if (cc) {
            if (cm) { fd[k] = fd[k-1]; fi[k] = fi[k-1]; }
            else    { fd[k] = d;       fi[k] = ci;      }
          }
          cc = cm;
        }
        if (cc) { fd[0] = d; fi[0] = ci; }
      }
    }
    float* orow = knn_out + (size_t)q * 66;   // fp32 output 1 (knn_feat)
    u16*   xrow = X0 + (size_t)q * 96;        // bf16 MLP input, Kpad=96
    float2 pp; pp.x = p.x; pp.y = p.y;
    *(float2*)(&orow[0]) = pp;
    *(u32*)(&xrow[0]) = pk2bf(p.x, p.y);
#pragma unroll
    for (int j = 0; j < 16; ++j) {
      int ci = fi[j];
      float2 m = mc[ci], v = mv[ci];
      *(float2*)(&orow[2 + 4*j]) = m;
      *(float2*)(&orow[4 + 4*j]) = v;
      *(u32*)(&xrow[2 + 4*j]) = pk2bf(m.x, m.y);
      *(u32*)(&xrow[4 + 4*j]) = pk2bf(v.x, v.y);
    }
#pragma unroll
    for (int c = 33; c < 48; ++c) ((u32*)xrow)[c] = 0;  // u16 cols 66..95
  }
}

// ---------- weight prep: fp32 [K][N] -> bf16 transposed [N][Kpad] ----------
__global__ __launch_bounds__(256)
void prep_wt_all(const float* __restrict__ w1, const float* __restrict__ w2,
                 const float* __restrict__ w3, const float* __restrict__ w4,
                 const float* __restrict__ w5,
                 u16* __restrict__ wt1, u16* __restrict__ wt2, u16* __restrict__ wt3,
                 u16* __restrict__ wt4, u16* __restrict__ wt5)
{
  const int l = blockIdx.y;
  const float* w; u16* wt; int K, N, Kp;
  if (l == 0)      { w = w1; wt = wt1; K = 66;  N = 128; Kp = 96;  }
  else if (l == 1) { w = w2; wt = wt2; K = 128; N = 256; Kp = 128; }
  else if (l == 2) { w = w3; wt = wt3; K = 256; N = 512; Kp = 256; }
  else if (l == 3) { w = w4; wt = wt4; K = 512; N = 128; Kp = 512; }
  else             { w = w5; wt = wt5; K = 128; N = 64;  Kp = 128; }
  int i = blockIdx.x * 256 + threadIdx.x;
  if (i >= N * Kp) return;
  int n = i / Kp, kp = i - n * Kp;
  float v = (kp < K) ? w[(size_t)kp * N + n] : 0.0f;
  wt[i] = f2bf(v);
}

// ---------- GEMM (bf16 MFMA, BM=128 x BN∈{64,128}) + fused BN+ReLU + stats ----------
// R11: R10's megakernel measured the truth — MLP VALU work is ~32 us (VALUBusy
// 2.1% of 1520 us) and grid.sync costs ~300 us/sync (dead end). So the R9
// chain's ~170 us is REAL in-kernel time, and the only surviving account is
// A-operand re-reads: BN=64 tiling re-read A grid.y times (~340 MB L3 traffic).
// Fix: BN=128 for layers 1-4 (A re-reads 8x->4x for L3, 2x->1x for L4, etc.;
// 340 -> 132 MB), keeping the R9 pipelined K-loop with LDS-staged B (removing
// it was R7's fatal mistake). 16 MFMAs per barrier instead of 8. LDS 49 KB ->
// 3 blocks/CU at BN=128. Identical arithmetic (same FUSE sequence, k-ascending
// MFMA chain, same epilogue).
template<int KW, int BN, bool FUSE>
__global__ __launch_bounds__(256, (BN == 64) ? 4 : 3)
void gemm_bn_kernel(const u16* __restrict__ X,
                    const u16* __restrict__ WT,
                    const float* __restrict__ bias,
                    const float* __restrict__ psum, const float* __restrict__ psq,
                    const float* __restrict__ gw,   const float* __restrict__ bw,
                    u16* __restrict__ Z, int N,
                    float* __restrict__ csum, float* __restrict__ csq)
{
  constexpr int BM = 128;
  constexpr int AST = 40;                 // 32 data + 8 pad (bf16)
  constexpr int NSTEP = KW / 32;
  __shared__ u16 Ash[2][BM * AST];
  __shared__ u16 Bsh[2][BN * AST];
  __shared__ float redS[4][BN];
  __shared__ float redQ[4][BN];
  __shared__ float scA[FUSE ? KW : 1];
  __shared__ float ttA[FUSE ? KW : 1];

  const int t = threadIdx.x;
  const int wave = t >> 6;
  const int lane = t & 63;
  const int lr = lane & 15;
  const int qd = lane >> 4;
  const int m0 = blockIdx.x * BM;
  const int n0 = blockIdx.y * BN;

  if (FUSE) {
    const float invB = 1.0f / 32768.0f;
    for (int c = t; c < KW; c += 256) {
      float mean = psum[c] * invB;
      float var  = __fmaf_rn(-mean, mean, psq[c] * invB);  // biased
      float sc   = gw[c] * rsqrtf(var + EPS_BN);
      scA[c] = sc;
      ttA[c] = __fmaf_rn(-mean, sc, bw[c]);
    }
    __syncthreads();                  // scA/ttA ready before prologue staging
  }

  f32x4 acc[2][BN / 16];
#pragma unroll
  for (int a = 0; a < 2; ++a)
#pragma unroll
    for (int b = 0; b < BN / 16; ++b) {
      acc[a][b][0] = 0.f; acc[a][b][1] = 0.f; acc[a][b][2] = 0.f; acc[a][b][3] = 0.f;
    }

  const int sr = t >> 2;          // 0..63
  const int sk = (t & 3) * 8;     // 0,8,16,24

  const u16* Arow0 = &X[(size_t)(m0 + sr) * KW + sk];
  const u16* Arow1 = &X[(size_t)(m0 + sr + 64) * KW + sk];
  const u16* Brow0 = &WT[(size_t)(n0 + sr) * KW + sk];
  const u16* Brow1 = (BN == 128) ? &WT[(size_t)(n0 + sr + 64) * KW + sk] : Brow0;

  // FUSE transform on a staged 8-elem group at columns kk..kk+7 (bit-identical
  // to the R8/R9 version: same fma/max/f2bf sequence per element).
  auto fuseq = [&](uint4 gv, int kk) -> uint4 {
    u32 w[4] = {gv.x, gv.y, gv.z, gv.w};
    u32 o[4];
#pragma unroll
    for (int e = 0; e < 4; ++e) {
      float lo = bf2f((u16)(w[e] & 0xffffu));
      float hi = bf2f((u16)(w[e] >> 16));
      float yl = fmaxf(__fmaf_rn(lo, scA[kk + 2 * e],     ttA[kk + 2 * e]),     0.0f);
      float yh = fmaxf(__fmaf_rn(hi, scA[kk + 2 * e + 1], ttA[kk + 2 * e + 1]), 0.0f);
      o[e] = (u32)f2bf(yl) | ((u32)f2bf(yh) << 16);
    }
    uint4 r; r.x = o[0]; r.y = o[1]; r.z = o[2]; r.w = o[3];
    return r;
  };

  // ---- prologue: tile 0 -> buf0; tile 1 -> registers
  {
    uint4 a0 = *(const uint4*)(Arow0);
    uint4 a1 = *(const uint4*)(Arow1);
    uint4 b0 = *(const uint4*)(Brow0);
    if (FUSE) { a0 = fuseq(a0, sk); a1 = fuseq(a1, sk); }
    *(uint4*)(&Ash[0][sr * AST + sk]) = a0;
    *(uint4*)(&Ash[0][(sr + 64) * AST + sk]) = a1;
    *(uint4*)(&Bsh[0][sr * AST + sk]) = b0;
    if (BN == 128) {
      uint4 b1 = *(const uint4*)(Brow1);
      *(uint4*)(&Bsh[0][(sr + 64) * AST + sk]) = b1;
    }
  }
  uint4 a0n = {}, a1n = {}, b0n = {}, b1n = {};   // regs: tile ts+1 during iter ts
  if (NSTEP > 1) {
    a0n = *(const uint4*)(Arow0 + 32);
    a1n = *(const uint4*)(Arow1 + 32);
    b0n = *(const uint4*)(Brow0 + 32);
    if (BN == 128) b1n = *(const uint4*)(Brow1 + 32);
  }
  __syncthreads();

  for (int ts = 0; ts < NSTEP; ++ts) {
    const int cur = ts & 1;

    // issue loads for tile ts+2 (consumed NEXT iteration -> full-iter latency cover)
    uint4 La0 = a0n, La1 = a1n, Lb0 = b0n, Lb1 = b1n;
    if (ts + 2 < NSTEP) {
      const int ko = (ts + 2) * 32;
      La0 = *(const uint4*)(Arow0 + ko);
      La1 = *(const uint4*)(Arow1 + ko);
      Lb0 = *(const uint4*)(Brow0 + ko);
      if (BN == 128) Lb1 = *(const uint4*)(Brow1 + ko);
    }

    bf16x8 af0 = *(const bf16x8*)(&Ash[cur][(wave * 32 + lr) * AST + qd * 8]);
    bf16x8 af1 = *(const bf16x8*)(&Ash[cur][(wave * 32 + 16 + lr) * AST + qd * 8]);
#pragma unroll
    for (int ct = 0; ct < BN / 16; ++ct) {
      bf16x8 bfr = *(const bf16x8*)(&Bsh[cur][(ct * 16 + lr) * AST + qd * 8]);
      acc[0][ct] = __builtin_amdgcn_mfma_f32_16x16x32_bf16(af0, bfr, acc[0][ct], 0, 0, 0);
      acc[1][ct] = __builtin_amdgcn_mfma_f32_16x16x32_bf16(af1, bfr, acc[1][ct], 0, 0, 0);
    }

    if (ts + 1 < NSTEP) {
      uint4 wa0 = a0n, wa1 = a1n;              // tile ts+1, loaded one iter ago
      if (FUSE) {
        const int kk = (ts + 1) * 32 + sk;
        wa0 = fuseq(wa0, kk);
        wa1 = fuseq(wa1, kk);
      }
      *(uint4*)(&Ash[cur ^ 1][sr * AST + sk]) = wa0;
      *(uint4*)(&Ash[cur ^ 1][(sr + 64) * AST + sk]) = wa1;
      *(uint4*)(&Bsh[cur ^ 1][sr * AST + sk]) = b0n;
      if (BN == 128) *(uint4*)(&Bsh[cur ^ 1][(sr + 64) * AST + sk]) = b1n;
      __syncthreads();                // one barrier per K-step; none after last
      a0n = La0; a1n = La1; b0n = Lb0; b1n = Lb1;
    }
  }

  // epilogue: bias, bf16 Z store, per-column partial sums
#pragma unroll
  for (int ct = 0; ct < BN / 16; ++ct) {
    int cg = n0 + ct * 16 + lr;
    float bv = bias[cg];
    float s = 0.f, sqv = 0.f;
#pragma unroll
    for (int rt = 0; rt < 2; ++rt) {
#pragma unroll
      for (int r = 0; r < 4; ++r) {
        float z = acc[rt][ct][r] + bv;
        int row = m0 + wave * 32 + rt * 16 + qd * 4 + r;  // C/D: row=quad*4+reg, col=lane&15
        Z[(size_t)row * N + cg] = f2bf(z);
        s += z;
        sqv = __fmaf_rn(z, z, sqv);
      }
    }
    s   += __shfl_xor(s, 16);   s   += __shfl_xor(s, 32);
    sqv += __shfl_xor(sqv, 16); sqv += __shfl_xor(sqv, 32);
    if (qd == 0) { redS[wave][ct * 16 + lr] = s; redQ[wave][ct * 16 + lr] = sqv; }
  }
  __syncthreads();
  if (t < BN) {
    float s  = redS[0][t] + redS[1][t] + redS[2][t] + redS[3][t];
    float sv = redQ[0][t] + redQ[1][t] + redQ[2][t] + redQ[3][t];
    atomicAdd(&csum[n0 + t], s);
    atomicAdd(&csq[n0 + t], sv);
  }
}

// ---------- final layer: fused BN5+ReLU + 64->2 GEMV, fp32 out ----------
__global__ __launch_bounds__(256)
void gemv6_kernel(const u16* __restrict__ Z5, const float* __restrict__ w6,
                  const float* __restrict__ b6,
                  const float* __restrict__ psum, const float* __restrict__ psq,
                  const float* __restrict__ gw,   const float* __restrict__ bw,
                  float* __restrict__ out)
{
  __shared__ float wsh[128];
  __shared__ float scs[64];
  __shared__ float tts[64];
  const int t = threadIdx.x;
  if (t < 128) wsh[t] = w6[t];
  if (t < 64) {
    const float invB = 1.0f / 32768.0f;
    float mean = psum[t] * invB;
    float var  = __fmaf_rn(-mean, mean, psq[t] * invB);
    float sc   = gw[t] * rsqrtf(var + EPS_BN);
    scs[t] = sc;
    tts[t] = __fmaf_rn(-mean, sc, bw[t]);
  }
  __syncthreads();
  const int q = blockIdx.x * 256 + t;
  const uint4* xv = (const uint4*)(Z5 + (size_t)q * 64);
  float a0 = 0.f, a1 = 0.f;
#pragma unroll
  for (int cc = 0; cc < 8; ++cc) {
    uint4 pk = xv[cc];
    u32 u[4] = {pk.x, pk.y, pk.z, pk.w};
#pragma unroll
    for (int uu = 0; uu < 4; ++uu) {
      int k = cc * 8 + uu * 2;
      float z0 = bf2f((u16)(u[uu] & 0xffffu));
      float z1 = bf2f((u16)(u[uu] >> 16));
      float x0 = fmaxf(__fmaf_rn(z0, scs[k],     tts[k]),     0.0f);
      float x1 = fmaxf(__fmaf_rn(z1, scs[k + 1], tts[k + 1]), 0.0f);
      x0 = bf2f(f2bf(x0));  // match prior bf16 round-trip of activations
      x1 = bf2f(f2bf(x1));
      a0 = __fmaf_rn(x0, wsh[2 * k + 0], a0);
      a1 = __fmaf_rn(x0, wsh[2 * k + 1], a1);
      a0 = __fmaf_rn(x1, wsh[2 * k + 2], a0);
      a1 = __fmaf_rn(x1, wsh[2 * k + 3], a1);
    }
  }
  float2 o; o.x = a0 + b6[0]; o.y = a1 + b6[1];
  ((float2*)out)[q] = o;
}

// ---------- launch ----------
extern "C" void kernel_launch(void* const* d_in, const int* in_sizes, int n_in,
                              void* d_out, int out_size, void* d_ws, size_t ws_size,
                              hipStream_t stream)
{
  const float2* pos = (const float2*)d_in[0];
  const float2* mc  = (const float2*)d_in[1];
  const float2* mv  = (const float2*)d_in[2];
  const float* w1 = (const float*)d_in[3];  const float* b1 = (const float*)d_in[4];
  const float* w2 = (const float*)d_in[5];  const float* b2 = (const float*)d_in[6];
  const float* w3 = (const float*)d_in[7];  const float* b3 = (const float*)d_in[8];
  const float* w4 = (const float*)d_in[9];  const float* b4 = (const float*)d_in[10];
  const float* w5 = (const float*)d_in[11]; const float* b5 = (const float*)d_in[12];
  const float* w6 = (const float*)d_in[13]; const float* b6 = (const float*)d_in[14];
  const float* g1 = (const float*)d_in[15]; const float* be1 = (const float*)d_in[16];
  const float* g2 = (const float*)d_in[17]; const float* be2 = (const float*)d_in[18];
  const float* g3 = (const float*)d_in[19]; const float* be3 = (const float*)d_in[20];
  const float* g4 = (const float*)d_in[21]; const float* be4 = (const float*)d_in[22];
  const float* g5 = (const float*)d_in[23]; const float* be5 = (const float*)d_in[24];

  // ws layout (bf16): X0 6.29MB | ZA 33.55MB | ZB 33.55MB | WT1..5 | stats
  char* ws = (char*)d_ws;
  u16* X0   = (u16*)(ws + 0);
  u16* ZA   = (u16*)(ws + 6291456);
  u16* ZB   = (u16*)(ws + 39845888);
  u16* WT1  = (u16*)(ws + 73400320);
  u16* WT2  = (u16*)(ws + 73424896);
  u16* WT3  = (u16*)(ws + 73490432);
  u16* WT4  = (u16*)(ws + 73752576);
  u16* WT5  = (u16*)(ws + 73883648);
  float* stats = (float*)(ws + 73900032);
  float* s1 = stats;        float* s2 = stats + 128;  float* s3 = stats + 384;
  float* s4 = stats + 896;  float* s5 = stats + 1024;
  float* sqb = stats + 1088;
  float* q1 = sqb;          float* q2 = sqb + 128;    float* q3 = sqb + 384;
  float* q4 = sqb + 896;    float* q5 = sqb + 1024;

  float* outX = (float*)d_out;
  float* outK = outX + 2 * B_ROWS;

  hipMemsetAsync(stats, 0, 2176 * sizeof(float), stream);
  prep_wt_all<<<dim3(512, 5), 256, 0, stream>>>(w1, w2, w3, w4, w5, WT1, WT2, WT3, WT4, WT5);
  knn_kernel<<<dim3(2048), 256, 0, stream>>>(pos, mc, mv, outK, X0);

  // BN=128 for layers 1-4: A re-read grid.y times -> total A traffic 340->132 MB
  gemm_bn_kernel<96,  128, false><<<dim3(256, 1), 256, 0, stream>>>(
      X0, WT1, b1, nullptr, nullptr, nullptr, nullptr, ZA, 128, s1, q1);
  gemm_bn_kernel<128, 128, true><<<dim3(256, 2), 256, 0, stream>>>(
      ZA, WT2, b2, s1, q1, g1, be1, ZB, 256, s2, q2);
  gemm_bn_kernel<256, 128, true><<<dim3(256, 4), 256, 0, stream>>>(
      ZB, WT3, b3, s2, q2, g2, be2, ZA, 512, s3, q3);
  gemm_bn_kernel<512, 128, true><<<dim3(256, 1), 256, 0, stream>>>(
      ZA, WT4, b4, s3, q3, g3, be3, ZB, 128, s4, q4);
  gemm_bn_kernel<128, 64,  true><<<dim3(256, 1), 256, 0, stream>>>(
      ZB, WT5, b5, s4, q4, g4, be4, ZA, 64, s5, q5);
  gemv6_kernel<<<dim3(128), 256, 0, stream>>>(ZA, w6, b6, s5, q5, g5, be5, outX);

  (void)in_sizes; (void)n_in; (void)out_size; (void)ws_size;
}